// Round 3
// baseline (113.963 us; speedup 1.0000x reference)
//
#include <hip/hip_runtime.h>
#include <hip/hip_bf16.h>

typedef float f32x4 __attribute__((ext_vector_type(4)));
typedef unsigned int u32x4 __attribute__((ext_vector_type(4)));
typedef short s16x8 __attribute__((ext_vector_type(8)));

#define L2E 1.44269504088896340736f

static __device__ __forceinline__ unsigned int bf16_rne(float f) {
    unsigned int u = __builtin_bit_cast(unsigned int, f);
    return (u + 0x7fffu + ((u >> 16) & 1u)) >> 16;
}
static __device__ __forceinline__ unsigned int pack_bf16x2(float lo, float hi) {
    return bf16_rne(lo) | (bf16_rne(hi) << 16);
}
static __device__ __forceinline__ unsigned int cvt_pk_bf16(float lo, float hi) {
    unsigned int r;
    asm("v_cvt_pk_bf16_f32 %0, %1, %2" : "=v"(r) : "v"(lo), "v"(hi));
    return r;
}

// ---------------------------------------------------------------------------
// Prep: q' = (q+pos)*(0.125*log2e) -> bf16 [b][t][c]; k' = (k+pos) -> [b][t][c];
//       v' = (v+pos) -> bf16 [b][c][t]  (natural layout)
// Q scale folds BOTH sqrt(sqrt(ch)) factors AND log2(e) so softmax is exp2-direct.
// ---------------------------------------------------------------------------
__global__ __launch_bounds__(256) void qkv_prep(const float* __restrict__ qkv,
                                                const float* __restrict__ pos,
                                                unsigned short* __restrict__ qs,
                                                unsigned short* __restrict__ kt,
                                                unsigned short* __restrict__ vt)
{
    __shared__ unsigned short QtS[64][72];
    __shared__ unsigned short KtS[64][72];
    const int b    = blockIdx.y;
    const int t0   = blockIdx.x * 64;
    const int i    = threadIdx.x;
    const int crow = i >> 2;          // 0..63 : channel row
    const int t16  = (i & 3) * 16;    // 0,16,32,48 : t offset
    const float QSCALE = 0.125f * L2E;

    float pr[16];
    {
        const f32x4* pp = reinterpret_cast<const f32x4*>(
            pos + ((size_t)(b * 64 + crow)) * 2048 + t0 + t16);
        #pragma unroll
        for (int j = 0; j < 4; ++j) {
            f32x4 v = __builtin_nontemporal_load(pp + j);
            pr[4*j+0] = v[0]; pr[4*j+1] = v[1]; pr[4*j+2] = v[2]; pr[4*j+3] = v[3];
        }
    }
    const float* qp = qkv + ((size_t)(b * 192 + crow)) * 2048 + t0 + t16;
    {   // Q -> LDS transposed, scaled
        #pragma unroll
        for (int j = 0; j < 4; ++j) {
            f32x4 v = __builtin_nontemporal_load(reinterpret_cast<const f32x4*>(qp) + j);
            #pragma unroll
            for (int e = 0; e < 4; ++e)
                QtS[t16 + 4*j + e][crow] =
                    (unsigned short)bf16_rne((v[e] + pr[4*j+e]) * QSCALE);
        }
    }
    {   // K -> LDS transposed
        const float* kp = qp + (size_t)64 * 2048;
        #pragma unroll
        for (int j = 0; j < 4; ++j) {
            f32x4 v = __builtin_nontemporal_load(reinterpret_cast<const f32x4*>(kp) + j);
            #pragma unroll
            for (int e = 0; e < 4; ++e)
                KtS[t16 + 4*j + e][crow] =
                    (unsigned short)bf16_rne(v[e] + pr[4*j+e]);
        }
    }
    {   // V: straight through, natural [c][t] layout
        const float* vp = qp + (size_t)128 * 2048;
        unsigned int vv[8];
        #pragma unroll
        for (int j = 0; j < 4; ++j) {
            f32x4 v = __builtin_nontemporal_load(reinterpret_cast<const f32x4*>(vp) + j);
            vv[2*j+0] = pack_bf16x2(v[0] + pr[4*j+0], v[1] + pr[4*j+1]);
            vv[2*j+1] = pack_bf16x2(v[2] + pr[4*j+2], v[3] + pr[4*j+3]);
        }
        unsigned short* dst = vt + ((size_t)(b * 64 + crow)) * 2048 + t0 + t16;
        reinterpret_cast<u32x4*>(dst)[0] = (u32x4){vv[0], vv[1], vv[2], vv[3]};
        reinterpret_cast<u32x4*>(dst)[1] = (u32x4){vv[4], vv[5], vv[6], vv[7]};
    }
    __syncthreads();
    {   // write out [t][c]
        const int trow = i >> 2;
        const int c16  = (i & 3) * 16;
        u32x4 a0 = *reinterpret_cast<const u32x4*>(&QtS[trow][c16]);
        u32x4 a1 = *reinterpret_cast<const u32x4*>(&QtS[trow][c16 + 8]);
        unsigned short* qd = qs + ((size_t)(b * 2048 + t0 + trow)) * 64 + c16;
        reinterpret_cast<u32x4*>(qd)[0] = a0;
        reinterpret_cast<u32x4*>(qd)[1] = a1;
        u32x4 b0 = *reinterpret_cast<const u32x4*>(&KtS[trow][c16]);
        u32x4 b1 = *reinterpret_cast<const u32x4*>(&KtS[trow][c16 + 8]);
        unsigned short* kd = kt + ((size_t)(b * 2048 + t0 + trow)) * 64 + c16;
        reinterpret_cast<u32x4*>(kd)[0] = b0;
        reinterpret_cast<u32x4*>(kd)[1] = b1;
    }
}

// ---------------------------------------------------------------------------
// Flash attention, swapped orientation (S^T = K·Q^T, O^T = V^T·P^T).
// Double-buffered LDS, 1 barrier/iter, mask kept in registers (1 tile ahead).
// ---------------------------------------------------------------------------
__global__ __launch_bounds__(256) void attn_kernel(const unsigned short* __restrict__ qs,
                                                   const unsigned short* __restrict__ kt,
                                                   const unsigned short* __restrict__ vt,
                                                   const void* __restrict__ maskp,
                                                   float* __restrict__ out)
{
    __shared__ unsigned short Klds[2][64][72];  // [buf][s_local][c]
    __shared__ unsigned short Vlds[2][64][72];  // [buf][c][s_local]

    const int b    = blockIdx.y;
    const int t0   = blockIdx.x * 64;
    const int tid  = threadIdx.x;
    const int wave = tid >> 6;
    const int lane = tid & 63;
    const int ln   = lane & 15;
    const int lg   = lane >> 4;

    // --- mask dtype detection (uniform): int32 0/1 has zero high bytes ---
    unsigned int accm = 0;
    {
        const unsigned int* mu = (const unsigned int*)maskp;
        #pragma unroll
        for (int j = 0; j < 16; ++j) accm |= mu[j];
    }
    const bool maskIsBool = (accm & 0xffffff00u) != 0u;

    // --- Q fragments (B-operand of swapped QK^T) ---
    const int tg = t0 + 16 * wave + ln;
    s16x8 qf[2];
    #pragma unroll
    for (int kc = 0; kc < 2; ++kc)
        qf[kc] = *reinterpret_cast<const s16x8*>(
            qs + ((size_t)(b * 2048 + tg)) * 64 + 32 * kc + 8 * lg);

    f32x4 acc[4];
    #pragma unroll
    for (int n = 0; n < 4; ++n) acc[n] = (f32x4){0.f, 0.f, 0.f, 0.f};
    float M = -3.0e38f, L = 0.0f;

    const int stRow = tid >> 2;
    const int stC16 = (tid & 3) * 16;
    const unsigned short* kbase = kt + ((size_t)(b * 2048 + stRow)) * 64 + stC16;
    const unsigned short* vbase = vt + ((size_t)(b * 64 + stRow)) * 2048 + stC16;
    // per-lane mask row base (element offset)
    const size_t mrowoff = ((size_t)b * 2048 + (size_t)tg) * 2048;

    unsigned int m_cur[4];

    // --- prologue: stage tile 0, load its mask ---
    {
        u32x4 ka0 = reinterpret_cast<const u32x4*>(kbase)[0];
        u32x4 ka1 = reinterpret_cast<const u32x4*>(kbase)[1];
        u32x4 va0 = reinterpret_cast<const u32x4*>(vbase)[0];
        u32x4 va1 = reinterpret_cast<const u32x4*>(vbase)[1];
        if (maskIsBool) {
            const unsigned char* mp = (const unsigned char*)maskp + mrowoff + 4 * lg;
            #pragma unroll
            for (int ti = 0; ti < 4; ++ti)
                m_cur[ti] = __builtin_nontemporal_load(
                    reinterpret_cast<const unsigned int*>(mp + 16 * ti));
        } else {
            const u32x4* mp = reinterpret_cast<const u32x4*>(
                (const unsigned int*)maskp + mrowoff + 4 * lg);
            #pragma unroll
            for (int ti = 0; ti < 4; ++ti) {
                u32x4 x = __builtin_nontemporal_load(mp + 4 * ti);
                m_cur[ti] = (x[0] ? 1u : 0u) | ((x[1] ? 1u : 0u) << 8) |
                            ((x[2] ? 1u : 0u) << 16) | ((x[3] ? 1u : 0u) << 24);
            }
        }
        *reinterpret_cast<u32x4*>(&Klds[0][stRow][stC16])     = ka0;
        *reinterpret_cast<u32x4*>(&Klds[0][stRow][stC16 + 8]) = ka1;
        *reinterpret_cast<u32x4*>(&Vlds[0][stRow][stC16])     = va0;
        *reinterpret_cast<u32x4*>(&Vlds[0][stRow][stC16 + 8]) = va1;
    }
    __syncthreads();

    int cur = 0;
    for (int st = 0; st < 32; ++st) {
        // --- issue prefetch of tile st+1 (K,V from ws; mask direct) ---
        u32x4 ka0, ka1, va0, va1;
        unsigned int m_nxt[4];
        const bool pf = (st < 31);
        if (pf) {
            const int s1 = (st + 1) * 64;
            const unsigned short* ks = kbase + (size_t)s1 * 64;
            const unsigned short* vs = vbase + s1;
            ka0 = reinterpret_cast<const u32x4*>(ks)[0];
            ka1 = reinterpret_cast<const u32x4*>(ks)[1];
            va0 = reinterpret_cast<const u32x4*>(vs)[0];
            va1 = reinterpret_cast<const u32x4*>(vs)[1];
            if (maskIsBool) {
                const unsigned char* mp = (const unsigned char*)maskp + mrowoff + s1 + 4 * lg;
                #pragma unroll
                for (int ti = 0; ti < 4; ++ti)
                    m_nxt[ti] = __builtin_nontemporal_load(
                        reinterpret_cast<const unsigned int*>(mp + 16 * ti));
            } else {
                const u32x4* mp = reinterpret_cast<const u32x4*>(
                    (const unsigned int*)maskp + mrowoff + s1 + 4 * lg);
                #pragma unroll
                for (int ti = 0; ti < 4; ++ti) {
                    u32x4 x = __builtin_nontemporal_load(mp + 4 * ti);
                    m_nxt[ti] = (x[0] ? 1u : 0u) | ((x[1] ? 1u : 0u) << 8) |
                                ((x[2] ? 1u : 0u) << 16) | ((x[3] ? 1u : 0u) << 24);
                }
            }
        }

        // --- QK^T (swapped): S^T[s][t]; lane: s = 16ti+4lg+r, t = tg ---
        f32x4 S[4];
        #pragma unroll
        for (int ti = 0; ti < 4; ++ti) S[ti] = (f32x4){0.f, 0.f, 0.f, 0.f};
        __builtin_amdgcn_s_setprio(1);
        #pragma unroll
        for (int kc = 0; kc < 2; ++kc) {
            #pragma unroll
            for (int ti = 0; ti < 4; ++ti) {
                s16x8 kf = *reinterpret_cast<const s16x8*>(
                    &Klds[cur][16 * ti + ln][32 * kc + 8 * lg]);
                S[ti] = __builtin_amdgcn_mfma_f32_16x16x32_bf16(kf, qf[kc], S[ti], 0, 0, 0);
            }
        }
        __builtin_amdgcn_s_setprio(0);

        // --- mask + online softmax (S already in log2 units) ---
        float p[4][4];
        #pragma unroll
        for (int ti = 0; ti < 4; ++ti) {
            #pragma unroll
            for (int r = 0; r < 4; ++r)
                p[ti][r] = ((m_cur[ti] >> (8 * r)) & 0xffu) ? -1e9f : S[ti][r];
        }
        float tm = fmaxf(fmaxf(fmaxf(p[0][0], p[0][1]), fmaxf(p[0][2], p[0][3])),
                         fmaxf(fmaxf(p[1][0], p[1][1]), fmaxf(p[1][2], p[1][3])));
        tm = fmaxf(tm, fmaxf(fmaxf(fmaxf(p[2][0], p[2][1]), fmaxf(p[2][2], p[2][3])),
                             fmaxf(fmaxf(p[3][0], p[3][1]), fmaxf(p[3][2], p[3][3]))));
        tm = fmaxf(tm, __shfl_xor(tm, 16, 64));
        tm = fmaxf(tm, __shfl_xor(tm, 32, 64));
        // T13: skip rescale when no lane's max grew (wave-uniform branch)
        if (!__all(tm <= M)) {
            const float Mn    = fmaxf(M, tm);
            const float alpha = exp2f(M - Mn);
            L *= alpha;
            #pragma unroll
            for (int n = 0; n < 4; ++n) acc[n] *= alpha;
            M = Mn;
        }
        float tsum = 0.f;
        #pragma unroll
        for (int ti = 0; ti < 4; ++ti)
            #pragma unroll
            for (int r = 0; r < 4; ++r) {
                p[ti][r] = exp2f(p[ti][r] - M);
                tsum += p[ti][r];
            }
        tsum += __shfl_xor(tsum, 16, 64);
        tsum += __shfl_xor(tsum, 32, 64);
        L += tsum;

        // --- pack P to bf16 (v_cvt_pk) and redistribute to PV B-frag layout ---
        unsigned int pk[4][2];
        #pragma unroll
        for (int ti = 0; ti < 4; ++ti) {
            pk[ti][0] = cvt_pk_bf16(p[ti][0], p[ti][1]);
            pk[ti][1] = cvt_pk_bf16(p[ti][2], p[ti][3]);
        }
        unsigned int pfr[2][4];
        #pragma unroll
        for (int kc2 = 0; kc2 < 2; ++kc2)
            #pragma unroll
            for (int a2 = 0; a2 < 2; ++a2)
                #pragma unroll
                for (int b2 = 0; b2 < 2; ++b2)
                    #pragma unroll
                    for (int e = 0; e < 2; ++e) {
                        int src = ln + 16 * (2 * (lg & 1) + e);
                        unsigned int v = (unsigned int)__shfl(
                            (int)pk[2 * kc2 + a2][b2], src, 64);
                        if ((lg >> 1) == a2) pfr[kc2][2 * e + b2] = v;
                    }

        // --- PV: O^T[c][t] += V^T · P^T ---
        __builtin_amdgcn_s_setprio(1);
        #pragma unroll
        for (int kc2 = 0; kc2 < 2; ++kc2) {
            union { unsigned int u[4]; s16x8 s; } pu;
            pu.u[0] = pfr[kc2][0]; pu.u[1] = pfr[kc2][1];
            pu.u[2] = pfr[kc2][2]; pu.u[3] = pfr[kc2][3];
            #pragma unroll
            for (int n = 0; n < 4; ++n) {
                s16x8 vf = *reinterpret_cast<const s16x8*>(
                    &Vlds[cur][16 * n + ln][32 * kc2 + 8 * lg]);
                acc[n] = __builtin_amdgcn_mfma_f32_16x16x32_bf16(vf, pu.s, acc[n], 0, 0, 0);
            }
        }
        __builtin_amdgcn_s_setprio(0);

        // --- write prefetched tile into the other buffer; single barrier ---
        if (pf) {
            *reinterpret_cast<u32x4*>(&Klds[cur ^ 1][stRow][stC16])     = ka0;
            *reinterpret_cast<u32x4*>(&Klds[cur ^ 1][stRow][stC16 + 8]) = ka1;
            *reinterpret_cast<u32x4*>(&Vlds[cur ^ 1][stRow][stC16])     = va0;
            *reinterpret_cast<u32x4*>(&Vlds[cur ^ 1][stRow][stC16 + 8]) = va1;
            #pragma unroll
            for (int ti = 0; ti < 4; ++ti) m_cur[ti] = m_nxt[ti];
            __syncthreads();
            cur ^= 1;
        }
    }

    // --- epilogue: normalize and store, coalesced along t ---
    const float inv = 1.0f / L;
    #pragma unroll
    for (int n = 0; n < 4; ++n)
        #pragma unroll
        for (int r = 0; r < 4; ++r)
            __builtin_nontemporal_store(
                acc[n][r] * inv,
                &out[((size_t)(b * 64 + 16 * n + 4 * lg + r)) * 2048 + t0 + 16 * wave + ln]);
}

extern "C" void kernel_launch(void* const* d_in, const int* in_sizes, int n_in,
                              void* d_out, int out_size, void* d_ws, size_t ws_size,
                              hipStream_t stream) {
    const float* qkv = (const float*)d_in[0];
    const float* pos = (const float*)d_in[1];
    const void*  msk = d_in[2];
    float* outp = (float*)d_out;
    unsigned short* ws = (unsigned short*)d_ws;
    const size_t PLANE = (size_t)16 * 2048 * 64;
    unsigned short* qs = ws;
    unsigned short* kt = ws + PLANE;
    unsigned short* vt = ws + 2 * PLANE;

    dim3 grid(2048 / 64, 16);
    qkv_prep<<<grid, 256, 0, stream>>>(qkv, pos, qs, kt, vt);
    attn_kernel<<<grid, 256, 0, stream>>>(qs, kt, vt, msk, outp);
}